// Round 6
// baseline (1386.200 us; speedup 1.0000x reference)
//
#include <hip/hip_runtime.h>

typedef __attribute__((ext_vector_type(8))) short short8;
typedef __attribute__((ext_vector_type(4))) float f32x4;

#define LNE 1e-5f

__device__ __forceinline__ unsigned short f2bf(float f) {
  union { float f; unsigned int u; } v; v.f = f;
  unsigned int r = v.u + 0x7fffu + ((v.u >> 16) & 1u);
  return (unsigned short)(r >> 16);
}
__device__ __forceinline__ float bf2f(unsigned short s) {
  union { unsigned int u; float f; } v; v.u = ((unsigned int)s) << 16;
  return v.f;
}
__device__ __forceinline__ unsigned int pk2(float a, float b) {
  return (unsigned int)f2bf(a) | ((unsigned int)f2bf(b) << 16);
}
__device__ __forceinline__ short8 ld8(const unsigned short* p, int k) {
  return *(const short8*)(p + k * 32);
}

// LDS-only barrier: drains LDS ops (cross-wave LDS visibility) but leaves
// global loads in flight across the barrier (vmcnt untouched). All inter-phase
// data flows through LDS; global memory is read-only weights/x, so vmcnt(0)
// drain (what __syncthreads emits) is semantically unnecessary. sched_barrier
// pins post-barrier LDS reads below the s_barrier.
__device__ __forceinline__ void bar_lds() {
  asm volatile("s_waitcnt lgkmcnt(0)" ::: "memory");
  __builtin_amdgcn_s_barrier();
  __builtin_amdgcn_sched_barrier(0);
}

// ---- weight prep: fp32 -> bf16, transposed to [n][k] ----
// ws layout (ushort elems):
//   wqkvT [1152][384]  rows: mat*384 + head*48 + e       (0 .. 442368)
//   woT   [384][384]   woT[n][d] = wo[d][n]              (442368 .. 589824)
//   w1T   [1536][384]  w1T[n][d] = w1[d][n]              (589824 .. 1179648)
//   w2T   [384][1536]  w2T[n][c] = w2[c][n]              (1179648 .. 1769472)
__global__ void prep_kernel(const float* __restrict__ wq, const float* __restrict__ wk,
                            const float* __restrict__ wv, const float* __restrict__ wo,
                            const float* __restrict__ w1, const float* __restrict__ w2,
                            unsigned short* __restrict__ ws) {
  int idx = blockIdx.x * 256 + threadIdx.x;
  if (idx < 442368) {
    int n = idx / 384, d = idx % 384;
    int mat = n / 384, rem = n % 384, head = rem / 48, e = rem % 48;
    const float* w = (mat == 0) ? wq : ((mat == 1) ? wk : wv);
    ws[idx] = f2bf(w[(head * 384 + d) * 48 + e]);
  } else if (idx < 589824) {
    int j = idx - 442368; int n = j / 384, d = j % 384;
    ws[idx] = f2bf(wo[d * 384 + n]);
  } else if (idx < 1179648) {
    int j = idx - 589824; int n = j / 384, d = j % 384;
    ws[idx] = f2bf(w1[d * 1536 + n]);
  } else if (idx < 1769472) {
    int j = idx - 1179648; int n = j / 1536, c = j % 1536;
    ws[idx] = f2bf(w2[c * 384 + n]);
  }
}

// ---- fused transformer block: one workgroup (512 thr / 8 waves) per batch ----
// R5: (a) lgkmcnt-only barriers so global weight prefetches survive phase
// boundaries; (b) every phase's first weight loads issued BEFORE the barrier
// that precedes it (QKV(hp+1) during SPV(hp), out-proj during last SPV,
// FFN1(0) during phase-2 epilogue, FFN2(c)/FFN1(c+2) inside the prior FFN
// iteration); (c) QKV balanced: every wave 9 MFMA-chains (streams w4, w4+4,
// + one mt-tile of stream 8).
__global__ __launch_bounds__(512, 2) void block_fused(
    const float* __restrict__ x,
    const float* __restrict__ bq, const float* __restrict__ bk, const float* __restrict__ bv,
    const float* __restrict__ bo, const float* __restrict__ b1, const float* __restrict__ b2,
    const float* __restrict__ g1, const float* __restrict__ be1,
    const float* __restrict__ g2, const float* __restrict__ be2,
    const unsigned short* __restrict__ wt,
    float* __restrict__ out) {
  __shared__ __align__(16) unsigned short sH[64 * 392];   // h after LN1; h2 after LN2
  __shared__ __align__(16) unsigned short sA[64 * 392];   // attn concat; U buffer 0
  __shared__ __align__(16) unsigned short sS[25344];      // qkv sets | LN2 scratch | U buffer 1

  const int tid  = threadIdx.x;
  const int wave = tid >> 6, lane = tid & 63;
  const int quad = lane >> 4, l15 = lane & 15;
  const int g = wave >> 2, w4 = wave & 3;    // head-set, wave-within-set
  const int b = blockIdx.x;

  const unsigned short* wqkvT = wt;
  const unsigned short* woT   = wt + 442368;
  const unsigned short* w1T   = wt + 589824;
  const unsigned short* w2T   = wt + 1179648;

  unsigned short* sQg = sS + g * 4608;
  unsigned short* sKg = sS + 9216 + g * 4608;
  unsigned short* sVg = sS + 18432 + g * 3456;

  // ---- QKV prefetch state (held across barriers) ----
  const unsigned short* qp0; const unsigned short* qp1; const unsigned short* qp2;
  short8 qb0[4], qb1[4], qb2[4];
  const int s0 = w4, s1 = w4 + 4;
  const int m0 = s0 / 3, e0 = s0 % 3;       // (0,0),(0,1),(0,2),(1,0)
  const int m1 = s1 / 3, e1 = s1 % 3;       // (1,1),(1,2),(2,0),(2,1)
  auto QKV_PRE = [&](int h) {
    qp0 = wqkvT + ((size_t)(m0 * 8 + h) * 48 + e0 * 16 + l15) * 384 + quad * 8;
    qp1 = wqkvT + ((size_t)(m1 * 8 + h) * 48 + e1 * 16 + l15) * 384 + quad * 8;
    qp2 = wqkvT + ((size_t)(16 + h) * 48 + 32 + l15) * 384 + quad * 8;
#pragma unroll
    for (int k = 0; k < 3; ++k) { qb0[k] = ld8(qp0, k); qb1[k] = ld8(qp1, k); qb2[k] = ld8(qp2, k); }
  };
  auto QKV_RUN = [&](int h) {
    f32x4 acc0[4], acc1[4], acc2 = (f32x4){0.f, 0.f, 0.f, 0.f};
#pragma unroll
    for (int mt = 0; mt < 4; ++mt) {
      acc0[mt] = (f32x4){0.f, 0.f, 0.f, 0.f};
      acc1[mt] = (f32x4){0.f, 0.f, 0.f, 0.f};
    }
    const unsigned short* abase  = sH + l15 * 392 + quad * 8;
    const unsigned short* abase2 = sH + (w4 * 16 + l15) * 392 + quad * 8;
#pragma unroll
    for (int k = 0; k < 12; ++k) {
      if (k < 9) {
        int sl = (k + 3) & 3;
        qb0[sl] = ld8(qp0, k + 3); qb1[sl] = ld8(qp1, k + 3); qb2[sl] = ld8(qp2, k + 3);
      }
      short8 a[4];
#pragma unroll
      for (int mt = 0; mt < 4; ++mt) a[mt] = *(const short8*)(abase + mt * 16 * 392 + k * 32);
      short8 a2 = *(const short8*)(abase2 + k * 32);
      int sl = k & 3;
#pragma unroll
      for (int mt = 0; mt < 4; ++mt)
        acc0[mt] = __builtin_amdgcn_mfma_f32_16x16x32_bf16(a[mt], qb0[sl], acc0[mt], 0, 0, 0);
#pragma unroll
      for (int mt = 0; mt < 4; ++mt)
        acc1[mt] = __builtin_amdgcn_mfma_f32_16x16x32_bf16(a[mt], qb1[sl], acc1[mt], 0, 0, 0);
      acc2 = __builtin_amdgcn_mfma_f32_16x16x32_bf16(a2, qb2[sl], acc2, 0, 0, 0);
    }
    auto wrStream = [&](int m, int e, f32x4* acc) {
      const float* bias = (m == 0) ? bq : ((m == 1) ? bk : bv);
      float bsv = bias[h * 48 + e * 16 + l15];
      if (m == 2) {    // v -> sVT[e][s], contiguous in s -> b64 pack
#pragma unroll
        for (int mt = 0; mt < 4; ++mt)
          *(uint2*)&sVg[(e * 16 + l15) * 72 + mt * 16 + quad * 4] =
              make_uint2(pk2(acc[mt][0] + bsv, acc[mt][1] + bsv),
                         pk2(acc[mt][2] + bsv, acc[mt][3] + bsv));
      } else {         // q/k -> [t][e], scalar scatter
        unsigned short* dst = (m == 0) ? sQg : sKg;
#pragma unroll
        for (int mt = 0; mt < 4; ++mt)
#pragma unroll
          for (int i = 0; i < 4; ++i)
            dst[(mt * 16 + quad * 4 + i) * 72 + e * 16 + l15] = f2bf(acc[mt][i] + bsv);
      }
    };
    wrStream(m0, e0, acc0);
    wrStream(m1, e1, acc1);
    {   // stream 8 = (v, et=2), own mt tile only
      float bsv = bv[h * 48 + 32 + l15];
      *(uint2*)&sVg[(32 + l15) * 72 + w4 * 16 + quad * 4] =
          make_uint2(pk2(acc2[0] + bsv, acc2[1] + bsv), pk2(acc2[2] + bsv, acc2[3] + bsv));
    }
  };

  // ---- out-proj prefetch state ----
  const unsigned short* obp[3]; short8 ob[3][4];

  // ================= Phase 0: LN1, x -> sH (bf16); zero q/k pads =================
  {
    {   // zero-pad q/k cols 48..63 of both sets (K=64 MFMA padding)
      int set = tid >> 8, j = tid & 255;
      int r = j >> 2, cc = 48 + (j & 3) * 4;
      *(uint2*)&sS[set * 4608 + r * 72 + cc] = make_uint2(0, 0);          // q pad
      *(uint2*)&sS[9216 + set * 4608 + r * 72 + cc] = make_uint2(0, 0);   // k pad
    }
    const int r = tid >> 3, sub = tid & 7;    // 8 threads per row
    const float* xr = x + ((size_t)b * 64 + r) * 384 + sub * 48;
    float s = 0.f, s2 = 0.f;
#pragma unroll
    for (int i = 0; i < 12; ++i) {
      float4 v = ((const float4*)xr)[i];
      s  += v.x + v.y + v.z + v.w;
      s2 += v.x * v.x + v.y * v.y + v.z * v.z + v.w * v.w;
    }
    s  += __shfl_xor(s, 1);  s  += __shfl_xor(s, 2);  s  += __shfl_xor(s, 4);
    s2 += __shfl_xor(s2, 1); s2 += __shfl_xor(s2, 2); s2 += __shfl_xor(s2, 4);
    float mu = s * (1.f / 384.f);
    float rstd = rsqrtf(s2 * (1.f / 384.f) - mu * mu + LNE);
#pragma unroll
    for (int i = 0; i < 12; ++i) {
      float4 v = ((const float4*)xr)[i];
      int c = sub * 48 + i * 4;
      float h0 = (v.x - mu) * rstd * g1[c + 0] + be1[c + 0];
      float h1 = (v.y - mu) * rstd * g1[c + 1] + be1[c + 1];
      float h2 = (v.z - mu) * rstd * g1[c + 2] + be1[c + 2];
      float h3 = (v.w - mu) * rstd * g1[c + 3] + be1[c + 3];
      *(uint2*)&sH[r * 392 + c] = make_uint2(pk2(h0, h1), pk2(h2, h3));
    }
  }
  QKV_PRE(g);          // hp=0 weight loads in flight across the barrier
  bar_lds();

  // ================= Phase 1: attention, 2 heads per iteration =================
#pragma unroll 1
  for (int hp = 0; hp < 4; ++hp) {
    const int h = hp * 2 + g;
    if (hp) {   // re-zero q pad (P overwrote all 64 cols last iter)
      int set = tid >> 8, j = tid & 255;
      int r = j >> 2, cc = 48 + (j & 3) * 4;
      *(uint2*)&sS[set * 4608 + r * 72 + cc] = make_uint2(0, 0);
    }
    QKV_RUN(h);
    if (hp < 3) QKV_PRE(h + 2);     // next-iter weights in flight across 2 barriers
    bar_lds();

    if (hp == 3) {                  // out-proj weights in flight during last SPV
#pragma unroll
      for (int nl = 0; nl < 3; ++nl) {
        obp[nl] = woT + (size_t)((wave * 3 + nl) * 16 + l15) * 384 + quad * 8;
#pragma unroll
        for (int k = 0; k < 3; ++k) ob[nl][k] = ld8(obp[nl], k);
      }
    }

    // --- S = q k^T (wave owns rows 16*w4..+15), causal softmax in-register ---
    f32x4 sc[4];
#pragma unroll
    for (int ts = 0; ts < 4; ++ts) {
      f32x4 acc = {0.f, 0.f, 0.f, 0.f};
#pragma unroll
      for (int k = 0; k < 2; ++k) {
        short8 a  = *(const short8*)&sQg[(w4 * 16 + l15) * 72 + k * 32 + quad * 8];
        short8 bb = *(const short8*)&sKg[(ts * 16 + l15) * 72 + k * 32 + quad * 8];
        acc = __builtin_amdgcn_mfma_f32_16x16x32_bf16(a, bb, acc, 0, 0, 0);
      }
      sc[ts] = acc;
    }
    const float scale = 0.14433756729740645f;  // 48^-0.5
#pragma unroll
    for (int i = 0; i < 4; ++i) {
      int t = w4 * 16 + quad * 4 + i;
      float vv[4];
#pragma unroll
      for (int ts = 0; ts < 4; ++ts) {
        int s_ = ts * 16 + l15;
        float v = sc[ts][i] * scale;
        vv[ts] = (s_ <= t) ? v : -INFINITY;
      }
      float mx = fmaxf(fmaxf(vv[0], vv[1]), fmaxf(vv[2], vv[3]));
      mx = fmaxf(mx, __shfl_xor(mx, 1)); mx = fmaxf(mx, __shfl_xor(mx, 2));
      mx = fmaxf(mx, __shfl_xor(mx, 4)); mx = fmaxf(mx, __shfl_xor(mx, 8));
      float sum = 0.f;
#pragma unroll
      for (int ts = 0; ts < 4; ++ts) { vv[ts] = __expf(vv[ts] - mx); sum += vv[ts]; }
      sum += __shfl_xor(sum, 1); sum += __shfl_xor(sum, 2);
      sum += __shfl_xor(sum, 4); sum += __shfl_xor(sum, 8);
      float inv = 1.f / sum;
#pragma unroll
      for (int ts = 0; ts < 4; ++ts)           // P -> sQ[t][s] (q is dead; own rows only)
        sQg[t * 72 + ts * 16 + l15] = f2bf(vv[ts] * inv);
    }
    // --- attn^T = V^T P^T ; write attn[t][h*48+e] (b64 pack) ---
#pragma unroll
    for (int et = 0; et < 3; ++et) {
      f32x4 acc = {0.f, 0.f, 0.f, 0.f};
#pragma unroll
      for (int k = 0; k < 2; ++k) {
        short8 a  = *(const short8*)&sVg[(et * 16 + l15) * 72 + k * 32 + quad * 8];
        short8 bb = *(const short8*)&sQg[(w4 * 16 + l15) * 72 + k * 32 + quad * 8];
        acc = __builtin_amdgcn_mfma_f32_16x16x32_bf16(a, bb, acc, 0, 0, 0);
      }
      *(uint2*)&sA[(w4 * 16 + l15) * 392 + h * 48 + et * 16 + quad * 4] =
          make_uint2(pk2(acc[0], acc[1]), pk2(acc[2], acc[3]));
    }
    bar_lds();
  }

  // ---- FFN prefetch state ----
  const unsigned short* f1p[3]; short8 f1a[3][4];
  const unsigned short* f2p[3]; short8 f2b[3][4];
  auto F1_PRE = [&](int c) {
#pragma unroll
    for (int ml = 0; ml < 3; ++ml) {
      f1p[ml] = w1T + (size_t)(c * 384 + (wave * 3 + ml) * 16 + l15) * 384 + quad * 8;
#pragma unroll
      for (int k = 0; k < 3; ++k) f1a[ml][k] = ld8(f1p[ml], k);
    }
  };
  auto F1_RUN = [&](int c, unsigned short* U) {
    f32x4 acc[3][4];
#pragma unroll
    for (int ml = 0; ml < 3; ++ml)
#pragma unroll
      for (int nt = 0; nt < 4; ++nt) acc[ml][nt] = (f32x4){0.f, 0.f, 0.f, 0.f};
#pragma unroll
    for (int k = 0; k < 12; ++k) {
      if (k < 9) {
        int sl = (k + 3) & 3;
#pragma unroll
        for (int ml = 0; ml < 3; ++ml) f1a[ml][sl] = ld8(f1p[ml], k + 3);
      }
      short8 bb[4];
#pragma unroll
      for (int nt = 0; nt < 4; ++nt)
        bb[nt] = *(const short8*)&sH[(nt * 16 + l15) * 392 + k * 32 + quad * 8];
      int sl = k & 3;
#pragma unroll
      for (int ml = 0; ml < 3; ++ml)
#pragma unroll
        for (int nt = 0; nt < 4; ++nt)
          acc[ml][nt] = __builtin_amdgcn_mfma_f32_16x16x32_bf16(f1a[ml][sl], bb[nt], acc[ml][nt], 0, 0, 0);
    }
#pragma unroll
    for (int ml = 0; ml < 3; ++ml) {
      int mt = wave * 3 + ml;
      int rbase = c * 384 + mt * 16 + quad * 4;
#pragma unroll
      for (int nt = 0; nt < 4; ++nt) {
        float u0 = fmaxf(acc[ml][nt][0] + b1[rbase + 0], 0.f);
        float u1 = fmaxf(acc[ml][nt][1] + b1[rbase + 1], 0.f);
        float u2 = fmaxf(acc[ml][nt][2] + b1[rbase + 2], 0.f);
        float u3 = fmaxf(acc[ml][nt][3] + b1[rbase + 3], 0.f);
        *(uint2*)&U[(nt * 16 + l15) * 392 + mt * 16 + quad * 4] =
            make_uint2(pk2(u0, u1), pk2(u2, u3));
      }
    }
  };
  f32x4 facc[4][3];
#pragma unroll
  for (int mt = 0; mt < 4; ++mt)
#pragma unroll
    for (int nl = 0; nl < 3; ++nl) facc[mt][nl] = (f32x4){0.f, 0.f, 0.f, 0.f};
  auto F2_PRE = [&](int c) {
#pragma unroll
    for (int nl = 0; nl < 3; ++nl) {
      f2p[nl] = w2T + (size_t)((wave * 3 + nl) * 16 + l15) * 1536 + c * 384 + quad * 8;
#pragma unroll
      for (int k = 0; k < 3; ++k) f2b[nl][k] = ld8(f2p[nl], k);
    }
  };
  auto F2_RUN = [&](int c, const unsigned short* U) {
#pragma unroll
    for (int k = 0; k < 12; ++k) {
      if (k < 9) {
        int sl = (k + 3) & 3;
#pragma unroll
        for (int nl = 0; nl < 3; ++nl) f2b[nl][sl] = ld8(f2p[nl], k + 3);
      }
      short8 a[4];
#pragma unroll
      for (int mt = 0; mt < 4; ++mt)
        a[mt] = *(const short8*)&U[(mt * 16 + l15) * 392 + k * 32 + quad * 8];
      int sl = k & 3;
#pragma unroll
      for (int nl = 0; nl < 3; ++nl)
#pragma unroll
        for (int mt = 0; mt < 4; ++mt)
          facc[mt][nl] = __builtin_amdgcn_mfma_f32_16x16x32_bf16(a[mt], f2b[nl][sl], facc[mt][nl], 0, 0, 0);
    }
  };

  // ================= Phase 2: out-proj + residual + LN2 =================
  {
    float* sRedS  = (float*)sS;        // qkv scratch dead -> LN2 cross-wave scratch
    float* sRedS2 = (float*)sS + 512;
    f32x4 oacc[3][4];
#pragma unroll
    for (int nl = 0; nl < 3; ++nl)
#pragma unroll
      for (int mt = 0; mt < 4; ++mt) oacc[nl][mt] = (f32x4){0.f, 0.f, 0.f, 0.f};
#pragma unroll
    for (int k = 0; k < 12; ++k) {
      if (k < 9) {
        int sl = (k + 3) & 3;
#pragma unroll
        for (int nl = 0; nl < 3; ++nl) ob[nl][sl] = ld8(obp[nl], k + 3);
      }
      short8 a[4];
#pragma unroll
      for (int mt = 0; mt < 4; ++mt)
        a[mt] = *(const short8*)&sA[(mt * 16 + l15) * 392 + k * 32 + quad * 8];
      int sl = k & 3;
#pragma unroll
      for (int nl = 0; nl < 3; ++nl)
#pragma unroll
        for (int mt = 0; mt < 4; ++mt)
          oacc[nl][mt] = __builtin_amdgcn_mfma_f32_16x16x32_bf16(a[mt], ob[nl][sl], oacc[nl][mt], 0, 0, 0);
    }
    // bias + residual
#pragma unroll
    for (int nl = 0; nl < 3; ++nl) {
      int n = (wave * 3 + nl) * 16 + l15;
      float bov = bo[n];
#pragma unroll
      for (int mt = 0; mt < 4; ++mt)
#pragma unroll
        for (int i = 0; i < 4; ++i)
          oacc[nl][mt][i] += bov + bf2f(sH[(mt * 16 + quad * 4 + i) * 392 + n]);
    }
    // per-wave partial row stats (48 cols) -> LDS -> combine 8 waves
#pragma unroll
    for (int mt = 0; mt < 4; ++mt)
#pragma unroll
      for (int i = 0; i < 4; ++i) {
        float s = oacc[0][mt][i] + oacc[1][mt][i] + oacc[2][mt][i];
        float s2 = oacc[0][mt][i] * oacc[0][mt][i] + oacc[1][mt][i] * oacc[1][mt][i]
                 + oacc[2][mt][i] * oacc[2][mt][i];
        s  += __shfl_xor(s, 1);  s  += __shfl_xor(s, 2);  s  += __shfl_xor(s, 4);  s  += __shfl_xor(s, 8);
        s2 += __shfl_xor(s2, 1); s2 += __shfl_xor(s2, 2); s2 += __shfl_xor(s2, 4); s2 += __shfl_xor(s2, 8);
        if (l15 == 0) {
          int row = mt * 16 + quad * 4 + i;
          sRedS[row * 8 + wave] = s;
          sRedS2[row * 8 + wave] = s2;
        }
      }
    bar_lds();
    float mu_[4][4], rs_[4][4];
#pragma unroll
    for (int mt = 0; mt < 4; ++mt)
#pragma unroll
      for (int i = 0; i < 4; ++i) {
        int row = mt * 16 + quad * 4 + i;
        float4 p0 = *(float4*)&sRedS[row * 8], p1 = *(float4*)&sRedS[row * 8 + 4];
        float4 q0 = *(float4*)&sRedS2[row * 8], q1 = *(float4*)&sRedS2[row * 8 + 4];
        float st  = p0.x + p0.y + p0.z + p0.w + p1.x + p1.y + p1.z + p1.w;
        float s2t = q0.x + q0.y + q0.z + q0.w + q1.x + q1.y + q1.z + q1.w;
        float mu = st * (1.f / 384.f);
        mu_[mt][i] = mu;
        rs_[mt][i] = rsqrtf(s2t * (1.f / 384.f) - mu * mu + LNE);
      }
#pragma unroll
    for (int nl = 0; nl < 3; ++nl) {
      int n = (wave * 3 + nl) * 16 + l15;
      float gv = g2[n], bev = be2[n];
#pragma unroll
      for (int mt = 0; mt < 4; ++mt)
#pragma unroll
        for (int i = 0; i < 4; ++i) {
          float h2v = (oacc[nl][mt][i] - mu_[mt][i]) * rs_[mt][i] * gv + bev;
          sH[(mt * 16 + quad * 4 + i) * 392 + n] = f2bf(h2v);   // h2 (own rows x cols region)
        }
    }
  }
  F1_PRE(0);           // FFN1 chunk-0 weights in flight across the barrier
  bar_lds();

  // ================= Phase 3: FFN, double-buffered chunks of 384 over 1536 =================
  F1_RUN(0, sA);
  F2_PRE(0);
  F1_PRE(1);
  bar_lds();
#pragma unroll 1
  for (int c = 0; c < 4; ++c) {
    if (c < 3) F1_RUN(c + 1, (c & 1) ? sA : sS);  // write next chunk to the other buffer
    F2_RUN(c, (c & 1) ? sS : sA);                 // read current chunk
    if (c < 3) {
      F2_PRE(c + 1);
      if (c < 2) F1_PRE(c + 2);
      bar_lds();
    }
  }

  // ================= Epilogue: out = h2 + ff + b2 =================
#pragma unroll
  for (int nl = 0; nl < 3; ++nl) {
    int n = (wave * 3 + nl) * 16 + l15;
    float b2v = b2[n];
#pragma unroll
    for (int mt = 0; mt < 4; ++mt) {
#pragma unroll
      for (int i = 0; i < 4; ++i) {
        int t = mt * 16 + quad * 4 + i;
        float v = facc[mt][nl][i] + b2v + bf2f(sH[t * 392 + n]);
        out[((size_t)b * 64 + t) * 384 + n] = v;
      }
    }
  }
}

extern "C" void kernel_launch(void* const* d_in, const int* in_sizes, int n_in,
                              void* d_out, int out_size, void* d_ws, size_t ws_size,
                              hipStream_t stream) {
  const float* x   = (const float*)d_in[0];
  const float* wq  = (const float*)d_in[1];
  const float* bq  = (const float*)d_in[2];
  const float* wk  = (const float*)d_in[3];
  const float* bk  = (const float*)d_in[4];
  const float* wv  = (const float*)d_in[5];
  const float* bv  = (const float*)d_in[6];
  const float* wo  = (const float*)d_in[7];
  const float* bo  = (const float*)d_in[8];
  const float* w1  = (const float*)d_in[9];
  const float* b1  = (const float*)d_in[10];
  const float* w2  = (const float*)d_in[11];
  const float* b2  = (const float*)d_in[12];
  const float* g1  = (const float*)d_in[13];
  const float* be1 = (const float*)d_in[14];
  const float* g2  = (const float*)d_in[15];
  const float* be2 = (const float*)d_in[16];
  unsigned short* wt = (unsigned short*)d_ws;
  float* out = (float*)d_out;

  int nbatch = in_sizes[0] / (64 * 384);    // 2048
  prep_kernel<<<(1769472 + 255) / 256, 256, 0, stream>>>(wq, wk, wv, wo, w1, w2, wt);
  block_fused<<<nbatch, 512, 0, stream>>>(x, bq, bk, bv, bo, b1, b2,
                                          g1, be1, g2, be2, wt, out);
}